// Round 1
// baseline (201.352 us; speedup 1.0000x reference)
//
#include <hip/hip_runtime.h>
#include <hip/hip_bf16.h>

typedef __bf16 bf16_t;
typedef __bf16 bf16x8 __attribute__((ext_vector_type(8)));
typedef float  f32x4  __attribute__((ext_vector_type(4)));

static __device__ __forceinline__ f32x4 mfma16(bf16x8 a, bf16x8 b, f32x4 c) {
    return __builtin_amdgcn_mfma_f32_16x16x32_bf16(a, b, c, 0, 0, 0);
}

// ---------------------------------------------------------------------------
// Pack W1_edge rows [128..160) and W2 [256x256] into bf16 MFMA B-fragment
// order: frag[(kstep*16 + ct)*64 + lane][j] = W[kstep*32 + 8*(lane>>4)+j][ct*16 + (lane&15)]
// ---------------------------------------------------------------------------
__global__ void prep_pack(const float* __restrict__ W1, const float* __restrict__ W2,
                          bf16_t* __restrict__ W1ef, bf16_t* __restrict__ W2f) {
    int t = blockIdx.x * blockDim.x + threadIdx.x;
    int l = t & 63;
    int g = l >> 4;
    int c = l & 15;
    if (t < 1024) {                       // W1 edge part: 16 col-tiles x 64 lanes
        int ct = t >> 6;
        #pragma unroll
        for (int j = 0; j < 8; ++j)
            W1ef[t * 8 + j] = (bf16_t)W1[(128 + 8 * g + j) * 256 + ct * 16 + c];
    } else if (t < 1024 + 8192) {         // W2: 8 ksteps x 16 col-tiles x 64 lanes
        int t2 = t - 1024;
        int ks = t2 >> 10;
        int ct = (t2 >> 6) & 15;
        #pragma unroll
        for (int j = 0; j < 8; ++j)
            W2f[t2 * 8 + j] = (bf16_t)W2[(ks * 32 + 8 * g + j) * 256 + ct * 16 + c];
    }
}

// ---------------------------------------------------------------------------
// Pi[b,i,h] = sum_d nodes[b,i,d] * W1[d,h] + b1[h]
// Pj[b,j,h] = sum_d nodes[b,j,d] * W1[160+d,h]
// grid: 128 b x 4 quarters of 16 rows; 256 threads = h
// ---------------------------------------------------------------------------
__global__ __launch_bounds__(256) void prep_pij(const float* __restrict__ nodes,
                                                const float* __restrict__ W1,
                                                const float* __restrict__ b1,
                                                float* __restrict__ Pi,
                                                float* __restrict__ Pj) {
    int b = blockIdx.x >> 2;
    int q = blockIdx.x & 3;
    int h = threadIdx.x;
    const float* nb = nodes + (b * 64 + q * 16) * 128;
    float ai[16], aj[16];
    float bias = b1[h];
    #pragma unroll
    for (int ii = 0; ii < 16; ++ii) { ai[ii] = bias; aj[ii] = 0.f; }
    for (int d = 0; d < 128; ++d) {
        float wi = W1[d * 256 + h];
        float wj = W1[(160 + d) * 256 + h];
        #pragma unroll
        for (int ii = 0; ii < 16; ++ii) {
            float s = nb[ii * 128 + d];   // uniform -> scalar load
            ai[ii] = fmaf(s, wi, ai[ii]);
            aj[ii] = fmaf(s, wj, aj[ii]);
        }
    }
    #pragma unroll
    for (int ii = 0; ii < 16; ++ii) {
        Pi[(b * 64 + q * 16 + ii) * 256 + h] = ai[ii];
        Pj[(b * 64 + q * 16 + ii) * 256 + h] = aj[ii];
    }
}

// ---------------------------------------------------------------------------
// Main fused MLP. Block = 128 pairs (2 source nodes i, all 64 j).
// 8 waves: rg = wave>>2 (row half, 64 rows), cg = wave&3 (64-col slice).
// ---------------------------------------------------------------------------
__global__ __launch_bounds__(512, 2) void mlp_main(
    const float* __restrict__ edges,
    const float* __restrict__ Pi, const float* __restrict__ Pj,
    const bf16_t* __restrict__ W1ef, const bf16_t* __restrict__ W2f,
    const float* __restrict__ b2, const float* __restrict__ W3,
    const float* __restrict__ b3, float* __restrict__ out) {

    __shared__ bf16_t a1[128][264];     // +8 bf16 pad: conflict-free-ish, keeps 16B align
    __shared__ float part[4][128];

    const int orig = blockIdx.x;
    const int blk = (orig & 7) * 512 + (orig >> 3);   // XCD-bijective swizzle (4096 % 8 == 0)
    const int b   = blk >> 5;
    const int ig2 = blk & 31;          // 32 chunks of 128 pairs per batch
    const int tid = threadIdx.x;
    const int w = tid >> 6;
    const int l = tid & 63;
    const int g = l >> 4, c = l & 15;
    const int rg = w >> 2, cg = w & 3;

    const long pbase = (long)b * 4096 + (long)ig2 * 128;

    // ---------------- layer 1: edges @ W1e ----------------
    const f32x4 z4 = {0.f, 0.f, 0.f, 0.f};
    f32x4 acc1[4][4];
    #pragma unroll
    for (int rt = 0; rt < 4; ++rt)
        #pragma unroll
        for (int ct = 0; ct < 4; ++ct) acc1[rt][ct] = z4;

    bf16x8 bf1[4];
    #pragma unroll
    for (int ct = 0; ct < 4; ++ct)
        bf1[ct] = *(const bf16x8*)&W1ef[((cg * 4 + ct) * 64 + l) * 8];

    #pragma unroll
    for (int rt = 0; rt < 4; ++rt) {
        const float* ep = edges + (pbase + rg * 64 + rt * 16 + c) * 32 + 8 * g;
        f32x4 e0 = *(const f32x4*)ep;
        f32x4 e1 = *(const f32x4*)(ep + 4);
        bf16x8 af;
        #pragma unroll
        for (int j = 0; j < 4; ++j) { af[j] = (bf16_t)e0[j]; af[4 + j] = (bf16_t)e1[j]; }
        #pragma unroll
        for (int ct = 0; ct < 4; ++ct)
            acc1[rt][ct] = mfma16(af, bf1[ct], acc1[rt][ct]);
    }

    // epilogue: + Pi + Pj (+b1 folded in Pi), relu, bf16 -> LDS
    {
        const float* Pib = Pi + ((long)b * 64 + ig2 * 2 + rg) * 256;
        const float* Pjb = Pj + (long)b * 64 * 256;
        #pragma unroll
        for (int ct = 0; ct < 4; ++ct) {
            int h = cg * 64 + ct * 16 + c;
            float piv = Pib[h];
            #pragma unroll
            for (int rt = 0; rt < 4; ++rt) {
                #pragma unroll
                for (int r = 0; r < 4; ++r) {
                    int row = rg * 64 + rt * 16 + 4 * g + r;
                    int j = row & 63;
                    float v = acc1[rt][ct][r] + piv + Pjb[j * 256 + h];
                    v = v > 0.f ? v : 0.f;
                    a1[row][h] = (bf16_t)v;
                }
            }
        }
    }
    __syncthreads();

    // ---------------- layer 2: a1 @ W2 ----------------
    f32x4 acc2[4][4];
    #pragma unroll
    for (int rt = 0; rt < 4; ++rt)
        #pragma unroll
        for (int ct = 0; ct < 4; ++ct) acc2[rt][ct] = z4;

    #pragma unroll
    for (int ks = 0; ks < 8; ++ks) {
        bf16x8 bf[4], af[4];
        #pragma unroll
        for (int ct = 0; ct < 4; ++ct)
            bf[ct] = *(const bf16x8*)&W2f[((ks * 16 + cg * 4 + ct) * 64 + l) * 8];
        #pragma unroll
        for (int rt = 0; rt < 4; ++rt)
            af[rt] = *(const bf16x8*)&a1[rg * 64 + rt * 16 + c][ks * 32 + 8 * g];
        #pragma unroll
        for (int rt = 0; rt < 4; ++rt)
            #pragma unroll
            for (int ct = 0; ct < 4; ++ct)
                acc2[rt][ct] = mfma16(af[rt], bf[ct], acc2[rt][ct]);
    }

    // ---------------- layer 3: relu(a2 + b2) @ W3 + b3 ----------------
    float b2v[4], w3v[4];
    #pragma unroll
    for (int ct = 0; ct < 4; ++ct) {
        int h = cg * 64 + ct * 16 + c;
        b2v[ct] = b2[h];
        w3v[ct] = W3[h];
    }
    const float bias3 = b3[0];

    #pragma unroll
    for (int rt = 0; rt < 4; ++rt) {
        #pragma unroll
        for (int r = 0; r < 4; ++r) {
            float s = 0.f;
            #pragma unroll
            for (int ct = 0; ct < 4; ++ct) {
                float v = acc2[rt][ct][r] + b2v[ct];
                v = v > 0.f ? v : 0.f;
                s = fmaf(v, w3v[ct], s);
            }
            s += __shfl_xor(s, 1);
            s += __shfl_xor(s, 2);
            s += __shfl_xor(s, 4);
            s += __shfl_xor(s, 8);
            if (c == 0) part[cg][rg * 64 + rt * 16 + 4 * g + r] = s;
        }
    }
    __syncthreads();

    if (tid < 128)
        out[pbase + tid] = part[0][tid] + part[1][tid] + part[2][tid] + part[3][tid] + bias3;
}

extern "C" void kernel_launch(void* const* d_in, const int* in_sizes, int n_in,
                              void* d_out, int out_size, void* d_ws, size_t ws_size,
                              hipStream_t stream) {
    const float* nodes = (const float*)d_in[0];
    const float* edges = (const float*)d_in[1];
    const float* W1    = (const float*)d_in[2];
    const float* b1    = (const float*)d_in[3];
    const float* W2    = (const float*)d_in[4];
    const float* b2    = (const float*)d_in[5];
    const float* W3    = (const float*)d_in[6];
    const float* b3    = (const float*)d_in[7];
    float* out = (float*)d_out;

    char* ws = (char*)d_ws;
    float*  Pi   = (float*)ws;                                   // 8 MB
    float*  Pj   = (float*)(ws + (size_t)8 * 1024 * 1024);       // 8 MB
    bf16_t* W2f  = (bf16_t*)(ws + (size_t)16 * 1024 * 1024);     // 128 KB
    bf16_t* W1ef = (bf16_t*)(ws + (size_t)16 * 1024 * 1024 + 131072); // 16 KB

    prep_pack<<<dim3(36), dim3(256), 0, stream>>>(W1, W2, W1ef, W2f);
    prep_pij<<<dim3(512), dim3(256), 0, stream>>>(nodes, W1, b1, Pi, Pj);
    mlp_main<<<dim3(4096), dim3(512), 0, stream>>>(edges, Pi, Pj, W1ef, W2f, b2, W3, b3, out);
}